// Round 5
// baseline (143.056 us; speedup 1.0000x reference)
//
#include <hip/hip_runtime.h>

#define BB 64
#define CC 256
#define HW 3136            // 56*56
#define VEC4 (HW / 4)      // 784 float4 per plane = 12*64 + 16
#define NROW (BB * CC)     // 16384
#define NBLK (BB * 16)     // 1024 blocks: (batch, 16-channel group)

typedef float f32x4 __attribute__((ext_vector_type(4)));

// One block = (batch b, channel-group cg of 16 channels).
// 4 waves; wave w streams channels cg*16+4w .. +3 (copy x->out, s/ss reduce).
// Group stats (g=2,4,8,16) computed in-block; BN via last-block reduction.
__global__ __launch_bounds__(256) void fused_kernel(
    const float* __restrict__ x, float* __restrict__ out,
    float* __restrict__ s_ws, float* __restrict__ ss_ws,
    unsigned int* __restrict__ cnt) {
  const int b    = blockIdx.x >> 4;
  const int cg   = blockIdx.x & 15;
  const int wv   = threadIdx.x >> 6;
  const int lane = threadIdx.x & 63;
  const int t    = threadIdx.x;

  __shared__ float s_l[16], ss_l[16];
  __shared__ float s2l[8], ss2l[8], s4l[4], ss4l[4], s8l[2], ss8l[2];
  __shared__ bool last;

  // ---- stream 4 planes per wave: copy + per-channel sum/sumsq ----
#pragma unroll
  for (int r = 0; r < 4; ++r) {
    const int ch_in_blk = wv * 4 + r;
    const size_t base = ((size_t)(b * CC + cg * 16 + ch_in_blk)) * HW;
    const f32x4* __restrict__ xv = (const f32x4*)(x + base);
    f32x4* __restrict__ ov = (f32x4*)(out + base);

    f32x4 v0, v1, v2, v3, v4, v5, v6, v7, v8, v9, v10, v11, vt;
    v0  = __builtin_nontemporal_load(&xv[lane +  0 * 64]);
    v1  = __builtin_nontemporal_load(&xv[lane +  1 * 64]);
    v2  = __builtin_nontemporal_load(&xv[lane +  2 * 64]);
    v3  = __builtin_nontemporal_load(&xv[lane +  3 * 64]);
    v4  = __builtin_nontemporal_load(&xv[lane +  4 * 64]);
    v5  = __builtin_nontemporal_load(&xv[lane +  5 * 64]);
    v6  = __builtin_nontemporal_load(&xv[lane +  6 * 64]);
    v7  = __builtin_nontemporal_load(&xv[lane +  7 * 64]);
    v8  = __builtin_nontemporal_load(&xv[lane +  8 * 64]);
    v9  = __builtin_nontemporal_load(&xv[lane +  9 * 64]);
    v10 = __builtin_nontemporal_load(&xv[lane + 10 * 64]);
    v11 = __builtin_nontemporal_load(&xv[lane + 11 * 64]);
    const bool tail = lane < 16;
    if (tail) vt = __builtin_nontemporal_load(&xv[768 + lane]);

    float s = 0.f, ss = 0.f;
#define STEP(V, IDX)                                            \
    __builtin_nontemporal_store(V, &ov[IDX]);                   \
    s += V.x + V.y + V.z + V.w;                                 \
    ss += V.x * V.x + V.y * V.y + V.z * V.z + V.w * V.w;
    STEP(v0,  lane +  0 * 64)
    STEP(v1,  lane +  1 * 64)
    STEP(v2,  lane +  2 * 64)
    STEP(v3,  lane +  3 * 64)
    STEP(v4,  lane +  4 * 64)
    STEP(v5,  lane +  5 * 64)
    STEP(v6,  lane +  6 * 64)
    STEP(v7,  lane +  7 * 64)
    STEP(v8,  lane +  8 * 64)
    STEP(v9,  lane +  9 * 64)
    STEP(v10, lane + 10 * 64)
    STEP(v11, lane + 11 * 64)
    if (tail) {
      STEP(vt, 768 + lane)
    }
#undef STEP

    for (int off = 32; off; off >>= 1) {
      s += __shfl_down(s, off, 64);
      ss += __shfl_down(ss, off, 64);
    }
    if (lane == 0) { s_l[ch_in_blk] = s; ss_l[ch_in_blk] = ss; }
  }
  __syncthreads();

  // ---- output layout ----
  const size_t OX = (size_t)NROW * HW;
  float* mean_bn = out + OX;                 // [C]
  float* var_bn  = mean_bn + CC;             // [C]
  float* m2  = var_bn + CC;                  // [B, 128]
  float* v2o = m2 + BB * 128;
  float* m4  = v2o + BB * 128;               // [B, 64]
  float* v4o = m4 + BB * 64;
  float* m8  = v4o + BB * 64;                // [B, 32]
  float* v8o = m8 + BB * 32;
  float* m16 = v8o + BB * 32;                // [B, 16]
  float* v16 = m16 + BB * 16;

  // per-(b,c) sums for BN
  if (t < 16) {
    s_ws[b * CC + cg * 16 + t]  = s_l[t];
    ss_ws[b * CC + cg * 16 + t] = ss_l[t];
  }

  // ---- hierarchical group stats (same pairwise order as reference) ----
  if (t < 8) {
    float s2 = s_l[2 * t] + s_l[2 * t + 1];
    float q2 = ss_l[2 * t] + ss_l[2 * t + 1];
    s2l[t] = s2; ss2l[t] = q2;
    const float inv = 1.f / (2.f * HW);
    const float m = s2 * inv;
    m2[b * 128 + cg * 8 + t]  = m;
    v2o[b * 128 + cg * 8 + t] = q2 * inv - m * m;
  }
  __syncthreads();
  if (t < 4) {
    float s4 = s2l[2 * t] + s2l[2 * t + 1];
    float q4 = ss2l[2 * t] + ss2l[2 * t + 1];
    s4l[t] = s4; ss4l[t] = q4;
    const float inv = 1.f / (4.f * HW);
    const float m = s4 * inv;
    m4[b * 64 + cg * 4 + t]  = m;
    v4o[b * 64 + cg * 4 + t] = q4 * inv - m * m;
  }
  __syncthreads();
  if (t < 2) {
    float s8 = s4l[2 * t] + s4l[2 * t + 1];
    float q8 = ss4l[2 * t] + ss4l[2 * t + 1];
    s8l[t] = s8; ss8l[t] = q8;
    const float inv = 1.f / (8.f * HW);
    const float m = s8 * inv;
    m8[b * 32 + cg * 2 + t]  = m;
    v8o[b * 32 + cg * 2 + t] = q8 * inv - m * m;
  }
  __syncthreads();
  if (t == 0) {
    float s16 = s8l[0] + s8l[1];
    float q16 = ss8l[0] + ss8l[1];
    const float inv = 1.f / (16.f * HW);
    const float m = s16 * inv;
    m16[b * 16 + cg] = m;
    v16[b * 16 + cg] = q16 * inv - m * m;
  }
  __syncthreads();   // all global stores issued (vmcnt drained at barrier)

  // ---- last-block BN reduction ----
  if (t == 0) {
    __threadfence();                                   // publish this XCD's L2
    last = (atomicAdd(cnt, 1u) == (unsigned)(NBLK - 1));
  }
  __syncthreads();
  if (last) {
    __threadfence();                                   // acquire
    float S = 0.f, SS = 0.f;
    for (int bb = 0; bb < BB; ++bb) {                  // coalesced: t = channel
      S  += s_ws[bb * CC + t];
      SS += ss_ws[bb * CC + t];
    }
    const float inv = 1.f / ((float)BB * (float)HW);
    const float m = S * inv;
    mean_bn[t] = m;
    var_bn[t]  = SS * inv - m * m;
  }
}

extern "C" void kernel_launch(void* const* d_in, const int* in_sizes, int n_in,
                              void* d_out, int out_size, void* d_ws, size_t ws_size,
                              hipStream_t stream) {
  const float* x = (const float*)d_in[0];
  float* out = (float*)d_out;
  float* s_ws = (float*)d_ws;                  // [B*C]
  float* ss_ws = s_ws + NROW;                  // [B*C]
  unsigned int* cnt = (unsigned int*)(ss_ws + NROW);

  hipMemsetAsync(cnt, 0, sizeof(unsigned int), stream);
  fused_kernel<<<NBLK, 256, 0, stream>>>(x, out, s_ws, ss_ws, cnt);
}